// Round 1
// baseline (722.360 us; speedup 1.0000x reference)
//
#include <hip/hip_runtime.h>
#include <hip/hip_fp16.h>

#define FDIM 64

__device__ __forceinline__ float rl(float v, int k) {
    return __int_as_float(__builtin_amdgcn_readlane(__float_as_int(v), k));
}
__device__ __forceinline__ float sigm(float x) { return 1.0f / (1.0f + __expf(-x)); }
__device__ __forceinline__ float tanhfast(float x) { return 1.0f - 2.0f / (__expf(2.0f * x) + 1.0f); }

// A = Wc @ Wl[0:64,:]  (64x64), bO = bc @ Wl[0:64,:] + bl
__global__ void k_precombine(const float* __restrict__ Wc, const float* __restrict__ bc,
                             const float* __restrict__ Wl, const float* __restrict__ bl,
                             float* __restrict__ A, float* __restrict__ bO) {
    int tid = blockIdx.x * blockDim.x + threadIdx.x;
    if (tid < 4096) {
        int k = tid >> 6, j = tid & 63;
        float acc = 0.f;
        for (int m = 0; m < 64; m++) acc += Wc[k * 64 + m] * Wl[m * 64 + j];
        A[tid] = acc;
    }
    if (tid < 64) {
        float acc = bl[tid];
        for (int m = 0; m < 64; m++) acc += bc[m] * Wl[m * 64 + tid];
        bO[tid] = acc;
    }
}

__global__ void k_deg_init(float* __restrict__ deg, int n) {
    int i = blockIdx.x * blockDim.x + threadIdx.x;
    if (i < n) deg[i] = 1.0f;   // self-loop weight
}

__global__ void k_deg_acc(const int* __restrict__ dst, const float* __restrict__ ew,
                          float* __restrict__ deg, int E) {
    int e = blockIdx.x * blockDim.x + threadIdx.x;
    if (e < E) unsafeAtomicAdd(&deg[dst[e]], ew[e]);
}

__global__ void k_dinv(float* __restrict__ deg, int n) {
    int i = blockIdx.x * blockDim.x + threadIdx.x;
    if (i < n) deg[i] = rsqrtf(deg[i]);   // deg >= 1 always (self-loop)
}

// agg[i][c] = dinv[i]^2 * x[i][c]
__global__ void k_agg_init(const float* __restrict__ x, const float* __restrict__ dinv,
                           float* __restrict__ agg, int total) {
    int g = blockIdx.x * blockDim.x + threadIdx.x;
    if (g < total) {
        float di = dinv[g >> 6];
        agg[g] = di * di * x[g];
    }
}

// per edge: agg[dst] += dinv[src]*ew*dinv[dst] * x[src]
__global__ void __launch_bounds__(256) k_edge(
        const int* __restrict__ src, const int* __restrict__ dst,
        const float* __restrict__ ew, const float* __restrict__ dinv,
        const float* __restrict__ x, float* __restrict__ agg, int E) {
    int lane = threadIdx.x & 63;
    int wid = __builtin_amdgcn_readfirstlane(threadIdx.x >> 6);
    long ebase = ((long)blockIdx.x * 4 + wid) * 8;
    if (ebase + 8 <= E) {
#pragma unroll
        for (int i = 0; i < 8; i++) {
            long e = ebase + i;
            int s = src[e], d = dst[e];
            float w = ew[e];
            float nrm = dinv[s] * w * dinv[d];
            float xv = x[(size_t)s * 64 + lane];
            unsafeAtomicAdd(&agg[(size_t)d * 64 + lane], nrm * xv);
        }
    } else {
        for (int i = 0; i < 8; i++) {
            long e = ebase + i;
            if (e >= E) break;
            int s = src[e], d = dst[e];
            float w = ew[e];
            float nrm = dinv[s] * w * dinv[d];
            float xv = x[(size_t)s * 64 + lane];
            unsafeAtomicAdd(&agg[(size_t)d * 64 + lane], nrm * xv);
        }
    }
}

// fused gates + head, wave-per-4-nodes, combined weights in LDS (fp16 pairs)
__global__ void __launch_bounds__(1024) k_node(
        const float* __restrict__ agg, const float* __restrict__ h,
        const float* __restrict__ Az, const float* __restrict__ Ar, const float* __restrict__ Ah,
        const float* __restrict__ bz, const float* __restrict__ br, const float* __restrict__ bh,
        const float* __restrict__ Wlz, const float* __restrict__ Wlr, const float* __restrict__ Wlh,
        const float* __restrict__ Whead, const float* __restrict__ bhead,
        float* __restrict__ out_head, float* __restrict__ out_h, int n_nodes) {

    __shared__ __half2 wZR_a[4096];  // (Az, Ar)[k][j]
    __shared__ __half2 wZR_h[4096];  // (Wlz[64+k][j], Wlr[64+k][j])
    __shared__ __half2 wH[4096];     // (Ah[k][j], Wlh[64+k][j])
    __shared__ float bzL[64], brL[64], bhL[64], whL[64];

    int tid = threadIdx.x;
    for (int idx = tid; idx < 4096; idx += 1024) {
        int k = idx >> 6, j = idx & 63;
        wZR_a[idx] = __floats2half2_rn(Az[idx], Ar[idx]);
        wZR_h[idx] = __floats2half2_rn(Wlz[(64 + k) * 64 + j], Wlr[(64 + k) * 64 + j]);
        wH[idx]    = __floats2half2_rn(Ah[idx], Wlh[(64 + k) * 64 + j]);
    }
    if (tid < 64) { bzL[tid] = bz[tid]; brL[tid] = br[tid]; bhL[tid] = bh[tid]; whL[tid] = Whead[tid]; }
    __syncthreads();

    int lane = tid & 63;
    int wave = (blockIdx.x << 4) + (tid >> 6);
    int nwaves = gridDim.x << 4;
    float bhead_v = bhead[0];

    for (int g = wave; g * 4 < n_nodes; g += nwaves) {
        size_t n0 = (size_t)g * 4;
        float a0 = agg[(n0 + 0) * 64 + lane];
        float a1 = agg[(n0 + 1) * 64 + lane];
        float a2 = agg[(n0 + 2) * 64 + lane];
        float a3 = agg[(n0 + 3) * 64 + lane];
        float h0v = h[(n0 + 0) * 64 + lane];
        float h1v = h[(n0 + 1) * 64 + lane];
        float h2v = h[(n0 + 2) * 64 + lane];
        float h3v = h[(n0 + 3) * 64 + lane];

        float z0 = 0, z1 = 0, z2 = 0, z3 = 0;
        float r0 = 0, r1 = 0, r2 = 0, r3 = 0;
        float t0 = 0, t1 = 0, t2 = 0, t3 = 0;
#pragma unroll 8
        for (int k = 0; k < 64; k++) {
            float2 za = __half22float2(wZR_a[k * 64 + lane]);
            float2 zh = __half22float2(wZR_h[k * 64 + lane]);
            float  ah = __low2float(wH[k * 64 + lane]);
            float ak, hk;
            ak = rl(a0, k); hk = rl(h0v, k);
            z0 += ak * za.x + hk * zh.x; r0 += ak * za.y + hk * zh.y; t0 += ak * ah;
            ak = rl(a1, k); hk = rl(h1v, k);
            z1 += ak * za.x + hk * zh.x; r1 += ak * za.y + hk * zh.y; t1 += ak * ah;
            ak = rl(a2, k); hk = rl(h2v, k);
            z2 += ak * za.x + hk * zh.x; r2 += ak * za.y + hk * zh.y; t2 += ak * ah;
            ak = rl(a3, k); hk = rl(h3v, k);
            z3 += ak * za.x + hk * zh.x; r3 += ak * za.y + hk * zh.y; t3 += ak * ah;
        }
        float bzv = bzL[lane], brv = brL[lane];
        float Z0 = sigm(z0 + bzv), Z1 = sigm(z1 + bzv), Z2 = sigm(z2 + bzv), Z3 = sigm(z3 + bzv);
        float hr0 = h0v * sigm(r0 + brv);
        float hr1 = h1v * sigm(r1 + brv);
        float hr2 = h2v * sigm(r2 + brv);
        float hr3 = h3v * sigm(r3 + brv);
#pragma unroll 8
        for (int k = 0; k < 64; k++) {
            float bhw = __high2float(wH[k * 64 + lane]);
            t0 += rl(hr0, k) * bhw;
            t1 += rl(hr1, k) * bhw;
            t2 += rl(hr2, k) * bhw;
            t3 += rl(hr3, k) * bhw;
        }
        float bhv = bhL[lane];
        float Ht0 = tanhfast(t0 + bhv), Ht1 = tanhfast(t1 + bhv);
        float Ht2 = tanhfast(t2 + bhv), Ht3 = tanhfast(t3 + bhv);
        float hn0 = Z0 * h0v + (1.f - Z0) * Ht0;
        float hn1 = Z1 * h1v + (1.f - Z1) * Ht1;
        float hn2 = Z2 * h2v + (1.f - Z2) * Ht2;
        float hn3 = Z3 * h3v + (1.f - Z3) * Ht3;
        out_h[(n0 + 0) * 64 + lane] = hn0;
        out_h[(n0 + 1) * 64 + lane] = hn1;
        out_h[(n0 + 2) * 64 + lane] = hn2;
        out_h[(n0 + 3) * 64 + lane] = hn3;

        float wv = whL[lane];
        float v0 = fmaxf(hn0, 0.f) * wv;
        float v1 = fmaxf(hn1, 0.f) * wv;
        float v2 = fmaxf(hn2, 0.f) * wv;
        float v3 = fmaxf(hn3, 0.f) * wv;
#pragma unroll
        for (int o = 32; o; o >>= 1) {
            v0 += __shfl_xor(v0, o);
            v1 += __shfl_xor(v1, o);
            v2 += __shfl_xor(v2, o);
            v3 += __shfl_xor(v3, o);
        }
        if (lane == 0) {
            out_head[n0 + 0] = v0 + bhead_v;
            out_head[n0 + 1] = v1 + bhead_v;
            out_head[n0 + 2] = v2 + bhead_v;
            out_head[n0 + 3] = v3 + bhead_v;
        }
    }
}

extern "C" void kernel_launch(void* const* d_in, const int* in_sizes, int n_in,
                              void* d_out, int out_size, void* d_ws, size_t ws_size,
                              hipStream_t stream) {
    const float* x     = (const float*)d_in[0];
    const int*   src   = (const int*)d_in[1];
    const int*   dst   = (const int*)d_in[2];
    const float* ew    = (const float*)d_in[3];
    const float* h     = (const float*)d_in[4];
    const float* Wcz   = (const float*)d_in[5];
    const float* bcz   = (const float*)d_in[6];
    const float* Wcr   = (const float*)d_in[7];
    const float* bcr   = (const float*)d_in[8];
    const float* Wch   = (const float*)d_in[9];
    const float* bch   = (const float*)d_in[10];
    const float* Wlz   = (const float*)d_in[11];
    const float* blz   = (const float*)d_in[12];
    const float* Wlr   = (const float*)d_in[13];
    const float* blr   = (const float*)d_in[14];
    const float* Wlh   = (const float*)d_in[15];
    const float* blh   = (const float*)d_in[16];
    const float* Whead = (const float*)d_in[17];
    const float* bhead = (const float*)d_in[18];

    int E = in_sizes[1];
    int n_nodes = in_sizes[4] / 64;          // 100000
    int total = n_nodes * 64;

    float* ws  = (float*)d_ws;
    float* deg = ws;                          // [n_nodes] -> later holds dinv
    float* agg = ws + n_nodes;                // [n_nodes*64]
    float* Az  = agg + (size_t)total;         // [4096]
    float* Ar  = Az + 4096;
    float* Ah  = Ar + 4096;
    float* bz  = Ah + 4096;
    float* br  = bz + 64;
    float* bh  = br + 64;

    float* out_head = (float*)d_out;          // [n_nodes]  (z reshaped B,N,1)
    float* out_h    = out_head + n_nodes;     // [n_nodes*64] (h0)

    k_precombine<<<16, 256, 0, stream>>>(Wcz, bcz, Wlz, blz, Az, bz);
    k_precombine<<<16, 256, 0, stream>>>(Wcr, bcr, Wlr, blr, Ar, br);
    k_precombine<<<16, 256, 0, stream>>>(Wch, bch, Wlh, blh, Ah, bh);

    k_deg_init<<<(n_nodes + 255) / 256, 256, 0, stream>>>(deg, n_nodes);
    k_deg_acc<<<(E + 255) / 256, 256, 0, stream>>>(dst, ew, deg, E);
    k_dinv<<<(n_nodes + 255) / 256, 256, 0, stream>>>(deg, n_nodes);
    k_agg_init<<<(total + 255) / 256, 256, 0, stream>>>(x, deg, agg, total);
    k_edge<<<(E + 31) / 32, 256, 0, stream>>>(src, dst, ew, deg, x, agg, E);
    k_node<<<512, 1024, 0, stream>>>(agg, h, Az, Ar, Ah, bz, br, bh,
                                     Wlz, Wlr, Wlh, Whead, bhead,
                                     out_head, out_h, n_nodes);
}

// Round 2
// 594.959 us; speedup vs baseline: 1.2141x; 1.2141x over previous
//
#include <hip/hip_runtime.h>
#include <hip/hip_fp16.h>
#include <stdint.h>

typedef unsigned long long u64;

__device__ __forceinline__ float rl(float v, int k) {
    return __int_as_float(__builtin_amdgcn_readlane(__float_as_int(v), k));
}
__device__ __forceinline__ float sigm(float x) { return 1.0f / (1.0f + __expf(-x)); }
__device__ __forceinline__ float tanhfast(float x) { return 1.0f - 2.0f / (__expf(2.0f * x) + 1.0f); }

// A = Wc @ Wl[0:64,:]  (64x64), bO = bc @ Wl[0:64,:] + bl
__global__ void k_precombine(const float* __restrict__ Wc, const float* __restrict__ bc,
                             const float* __restrict__ Wl, const float* __restrict__ bl,
                             float* __restrict__ A, float* __restrict__ bO) {
    int tid = blockIdx.x * blockDim.x + threadIdx.x;
    if (tid < 4096) {
        int k = tid >> 6, j = tid & 63;
        float acc = 0.f;
        for (int m = 0; m < 64; m++) acc += Wc[k * 64 + m] * Wl[m * 64 + j];
        A[tid] = acc;
    }
    if (tid < 64) {
        float acc = bl[tid];
        for (int m = 0; m < 64; m++) acc += bc[m] * Wl[m * 64 + tid];
        bO[tid] = acc;
    }
}

__global__ void k_init(float* __restrict__ deg, int* __restrict__ cnt, int* __restrict__ off, int n) {
    int i = blockIdx.x * blockDim.x + threadIdx.x;
    if (i < n) { deg[i] = 1.0f; cnt[i] = 0; }
    if (i == 0) off[0] = 0;
}

// weighted degree (float) + in-degree count (int)
__global__ void k_count(const int* __restrict__ dst, const float* __restrict__ ew,
                        float* __restrict__ deg, int* __restrict__ cnt, int E) {
    int e = blockIdx.x * blockDim.x + threadIdx.x;
    if (e < E) {
        int d = dst[e];
        unsafeAtomicAdd(&deg[d], ew[e]);
        atomicAdd(&cnt[d], 1);
    }
}

__global__ void k_dinv(float* __restrict__ deg, int n) {
    int i = blockIdx.x * blockDim.x + threadIdx.x;
    if (i < n) deg[i] = rsqrtf(deg[i]);   // deg >= 1 (self-loop)
}

// two-level scan: per-block inclusive scan of cnt into off[i+1], block sums out
__global__ void __launch_bounds__(1024) k_scan1(const int* __restrict__ cnt, int* __restrict__ off,
                                                int* __restrict__ bsum, int n) {
    __shared__ int sm[1024];
    int t = threadIdx.x;
    int i = blockIdx.x * 1024 + t;
    int v = (i < n) ? cnt[i] : 0;
    sm[t] = v; __syncthreads();
    for (int s = 1; s < 1024; s <<= 1) {
        int u = (t >= s) ? sm[t - s] : 0;
        __syncthreads();
        sm[t] += u;
        __syncthreads();
    }
    if (i < n) off[i + 1] = sm[t];
    if (t == 1023) bsum[blockIdx.x] = sm[1023];
}

// exclusive scan of block sums (nb <= 128)
__global__ void __launch_bounds__(128) k_scan2(int* __restrict__ bsum, int nb) {
    __shared__ int sm[128];
    int t = threadIdx.x;
    int v = (t < nb) ? bsum[t] : 0;
    sm[t] = v; __syncthreads();
    for (int s = 1; s < 128; s <<= 1) {
        int u = (t >= s) ? sm[t - s] : 0;
        __syncthreads();
        sm[t] += u;
        __syncthreads();
    }
    if (t < nb) bsum[t] = sm[t] - v;   // exclusive
}

__global__ void __launch_bounds__(1024) k_scan3(int* __restrict__ off, const int* __restrict__ bsum,
                                                int* __restrict__ cur, int n) {
    int i = blockIdx.x * 1024 + threadIdx.x;
    if (i < n) {
        int v = off[i + 1] + bsum[blockIdx.x];
        off[i + 1] = v;
        cur[i + 1] = v;
    }
    if (i == 0) cur[0] = 0;
}

// scatter packed (src, nrm) into CSR slots
__global__ void k_scatter(const int* __restrict__ src, const int* __restrict__ dst,
                          const float* __restrict__ ew, const float* __restrict__ dinv,
                          int* __restrict__ cur, u64* __restrict__ csr, int E) {
    int e = blockIdx.x * blockDim.x + threadIdx.x;
    if (e < E) {
        int s = src[e], d = dst[e];
        float nrm = dinv[s] * ew[e] * dinv[d];
        int p = atomicAdd(&cur[d], 1);
        csr[p] = (u64)(unsigned)s | ((u64)__float_as_uint(nrm) << 32);
    }
}

// one wave per dst node: acc = dinv^2*x[d] + sum nrm*x[src]; no atomics
__global__ void __launch_bounds__(256) k_gather(const int* __restrict__ off, const u64* __restrict__ csr,
                                                const float* __restrict__ dinv, const float* __restrict__ x,
                                                float* __restrict__ agg, int n) {
    int lane = threadIdx.x & 63;
    int wid = __builtin_amdgcn_readfirstlane(threadIdx.x >> 6);
    int d = blockIdx.x * 4 + wid;
    if (d >= n) return;
    int o0 = off[d], o1 = off[d + 1];
    float di = dinv[d];
    float acc0 = di * di * x[(size_t)d * 64 + lane];
    float acc1 = 0.f, acc2 = 0.f, acc3 = 0.f;
    int e = o0;
    for (; e + 4 <= o1; e += 4) {
        u64 m0 = csr[e + 0], m1 = csr[e + 1], m2 = csr[e + 2], m3 = csr[e + 3];
        int s0 = (int)(unsigned)m0, s1 = (int)(unsigned)m1;
        int s2 = (int)(unsigned)m2, s3 = (int)(unsigned)m3;
        float n0 = __uint_as_float((unsigned)(m0 >> 32));
        float n1 = __uint_as_float((unsigned)(m1 >> 32));
        float n2 = __uint_as_float((unsigned)(m2 >> 32));
        float n3 = __uint_as_float((unsigned)(m3 >> 32));
        float x0 = x[(size_t)s0 * 64 + lane];
        float x1 = x[(size_t)s1 * 64 + lane];
        float x2 = x[(size_t)s2 * 64 + lane];
        float x3 = x[(size_t)s3 * 64 + lane];
        acc0 += n0 * x0; acc1 += n1 * x1; acc2 += n2 * x2; acc3 += n3 * x3;
    }
    for (; e < o1; e++) {
        u64 m = csr[e];
        int s = (int)(unsigned)m;
        float nm = __uint_as_float((unsigned)(m >> 32));
        acc0 += nm * x[(size_t)s * 64 + lane];
    }
    agg[(size_t)d * 64 + lane] = (acc0 + acc1) + (acc2 + acc3);
}

// fused gates + head, wave-per-4-nodes, combined weights in LDS (fp16 pairs)
__global__ void __launch_bounds__(1024) k_node(
        const float* __restrict__ agg, const float* __restrict__ h,
        const float* __restrict__ Az, const float* __restrict__ Ar, const float* __restrict__ Ah,
        const float* __restrict__ bz, const float* __restrict__ br, const float* __restrict__ bh,
        const float* __restrict__ Wlz, const float* __restrict__ Wlr, const float* __restrict__ Wlh,
        const float* __restrict__ Whead, const float* __restrict__ bhead,
        float* __restrict__ out_head, float* __restrict__ out_h, int n_nodes) {

    __shared__ __half2 wZR_a[4096];  // (Az, Ar)[k][j]
    __shared__ __half2 wZR_h[4096];  // (Wlz[64+k][j], Wlr[64+k][j])
    __shared__ __half2 wH[4096];     // (Ah[k][j], Wlh[64+k][j])
    __shared__ float bzL[64], brL[64], bhL[64], whL[64];

    int tid = threadIdx.x;
    for (int idx = tid; idx < 4096; idx += 1024) {
        int k = idx >> 6, j = idx & 63;
        wZR_a[idx] = __floats2half2_rn(Az[idx], Ar[idx]);
        wZR_h[idx] = __floats2half2_rn(Wlz[(64 + k) * 64 + j], Wlr[(64 + k) * 64 + j]);
        wH[idx]    = __floats2half2_rn(Ah[idx], Wlh[(64 + k) * 64 + j]);
    }
    if (tid < 64) { bzL[tid] = bz[tid]; brL[tid] = br[tid]; bhL[tid] = bh[tid]; whL[tid] = Whead[tid]; }
    __syncthreads();

    int lane = tid & 63;
    int wave = (blockIdx.x << 4) + (tid >> 6);
    int nwaves = gridDim.x << 4;
    float bhead_v = bhead[0];

    for (int g = wave; g * 4 < n_nodes; g += nwaves) {
        size_t n0 = (size_t)g * 4;
        float a0 = agg[(n0 + 0) * 64 + lane];
        float a1 = agg[(n0 + 1) * 64 + lane];
        float a2 = agg[(n0 + 2) * 64 + lane];
        float a3 = agg[(n0 + 3) * 64 + lane];
        float h0v = h[(n0 + 0) * 64 + lane];
        float h1v = h[(n0 + 1) * 64 + lane];
        float h2v = h[(n0 + 2) * 64 + lane];
        float h3v = h[(n0 + 3) * 64 + lane];

        float z0 = 0, z1 = 0, z2 = 0, z3 = 0;
        float r0 = 0, r1 = 0, r2 = 0, r3 = 0;
        float t0 = 0, t1 = 0, t2 = 0, t3 = 0;
#pragma unroll 8
        for (int k = 0; k < 64; k++) {
            float2 za = __half22float2(wZR_a[k * 64 + lane]);
            float2 zh = __half22float2(wZR_h[k * 64 + lane]);
            float  ah = __low2float(wH[k * 64 + lane]);
            float ak, hk;
            ak = rl(a0, k); hk = rl(h0v, k);
            z0 += ak * za.x + hk * zh.x; r0 += ak * za.y + hk * zh.y; t0 += ak * ah;
            ak = rl(a1, k); hk = rl(h1v, k);
            z1 += ak * za.x + hk * zh.x; r1 += ak * za.y + hk * zh.y; t1 += ak * ah;
            ak = rl(a2, k); hk = rl(h2v, k);
            z2 += ak * za.x + hk * zh.x; r2 += ak * za.y + hk * zh.y; t2 += ak * ah;
            ak = rl(a3, k); hk = rl(h3v, k);
            z3 += ak * za.x + hk * zh.x; r3 += ak * za.y + hk * zh.y; t3 += ak * ah;
        }
        float bzv = bzL[lane], brv = brL[lane];
        float Z0 = sigm(z0 + bzv), Z1 = sigm(z1 + bzv), Z2 = sigm(z2 + bzv), Z3 = sigm(z3 + bzv);
        float hr0 = h0v * sigm(r0 + brv);
        float hr1 = h1v * sigm(r1 + brv);
        float hr2 = h2v * sigm(r2 + brv);
        float hr3 = h3v * sigm(r3 + brv);
#pragma unroll 8
        for (int k = 0; k < 64; k++) {
            float bhw = __high2float(wH[k * 64 + lane]);
            t0 += rl(hr0, k) * bhw;
            t1 += rl(hr1, k) * bhw;
            t2 += rl(hr2, k) * bhw;
            t3 += rl(hr3, k) * bhw;
        }
        float bhv = bhL[lane];
        float Ht0 = tanhfast(t0 + bhv), Ht1 = tanhfast(t1 + bhv);
        float Ht2 = tanhfast(t2 + bhv), Ht3 = tanhfast(t3 + bhv);
        float hn0 = Z0 * h0v + (1.f - Z0) * Ht0;
        float hn1 = Z1 * h1v + (1.f - Z1) * Ht1;
        float hn2 = Z2 * h2v + (1.f - Z2) * Ht2;
        float hn3 = Z3 * h3v + (1.f - Z3) * Ht3;
        out_h[(n0 + 0) * 64 + lane] = hn0;
        out_h[(n0 + 1) * 64 + lane] = hn1;
        out_h[(n0 + 2) * 64 + lane] = hn2;
        out_h[(n0 + 3) * 64 + lane] = hn3;

        float wv = whL[lane];
        float v0 = fmaxf(hn0, 0.f) * wv;
        float v1 = fmaxf(hn1, 0.f) * wv;
        float v2 = fmaxf(hn2, 0.f) * wv;
        float v3 = fmaxf(hn3, 0.f) * wv;
#pragma unroll
        for (int o = 32; o; o >>= 1) {
            v0 += __shfl_xor(v0, o);
            v1 += __shfl_xor(v1, o);
            v2 += __shfl_xor(v2, o);
            v3 += __shfl_xor(v3, o);
        }
        if (lane == 0) {
            out_head[n0 + 0] = v0 + bhead_v;
            out_head[n0 + 1] = v1 + bhead_v;
            out_head[n0 + 2] = v2 + bhead_v;
            out_head[n0 + 3] = v3 + bhead_v;
        }
    }
}

extern "C" void kernel_launch(void* const* d_in, const int* in_sizes, int n_in,
                              void* d_out, int out_size, void* d_ws, size_t ws_size,
                              hipStream_t stream) {
    const float* x     = (const float*)d_in[0];
    const int*   src   = (const int*)d_in[1];
    const int*   dst   = (const int*)d_in[2];
    const float* ew    = (const float*)d_in[3];
    const float* h     = (const float*)d_in[4];
    const float* Wcz   = (const float*)d_in[5];
    const float* bcz   = (const float*)d_in[6];
    const float* Wcr   = (const float*)d_in[7];
    const float* bcr   = (const float*)d_in[8];
    const float* Wch   = (const float*)d_in[9];
    const float* bch   = (const float*)d_in[10];
    const float* Wlz   = (const float*)d_in[11];
    const float* blz   = (const float*)d_in[12];
    const float* Wlr   = (const float*)d_in[13];
    const float* blr   = (const float*)d_in[14];
    const float* Wlh   = (const float*)d_in[15];
    const float* blh   = (const float*)d_in[16];
    const float* Whead = (const float*)d_in[17];
    const float* bhead = (const float*)d_in[18];

    int E = in_sizes[1];
    int n = in_sizes[4] / 64;                 // 100000 nodes
    int total = n * 64;

    // workspace layout
    float* ws  = (float*)d_ws;
    float* agg = ws;                          // n*64 f32
    float* deg = agg + (size_t)total;         // n f32 -> becomes dinv
    int*   cnt = (int*)(deg + n);             // n
    int*   off = cnt + n;                     // n+1
    int*   cur = off + n + 1;                 // n+1
    int*   bsum = cur + n + 1;                // 128
    u64*   csr = (u64*)(((uintptr_t)(bsum + 128) + 15) & ~(uintptr_t)15);  // E u64
    float* Az  = (float*)(csr + E);           // 4096
    float* Ar  = Az + 4096;
    float* Ah  = Ar + 4096;
    float* bz  = Ah + 4096;
    float* br  = bz + 64;
    float* bh  = br + 64;

    float* out_head = (float*)d_out;          // [n]  (z reshaped B,N,1)
    float* out_h    = out_head + n;           // [n*64] (h0)

    int nb = (n + 1023) / 1024;               // 98 <= 128

    k_precombine<<<16, 256, 0, stream>>>(Wcz, bcz, Wlz, blz, Az, bz);
    k_precombine<<<16, 256, 0, stream>>>(Wcr, bcr, Wlr, blr, Ar, br);
    k_precombine<<<16, 256, 0, stream>>>(Wch, bch, Wlh, blh, Ah, bh);

    k_init<<<(n + 255) / 256, 256, 0, stream>>>(deg, cnt, off, n);
    k_count<<<(E + 255) / 256, 256, 0, stream>>>(dst, ew, deg, cnt, E);
    k_dinv<<<(n + 255) / 256, 256, 0, stream>>>(deg, n);
    k_scan1<<<nb, 1024, 0, stream>>>(cnt, off, bsum, n);
    k_scan2<<<1, 128, 0, stream>>>(bsum, nb);
    k_scan3<<<nb, 1024, 0, stream>>>(off, bsum, cur, n);
    k_scatter<<<(E + 255) / 256, 256, 0, stream>>>(src, dst, ew, deg, cur, csr, E);
    k_gather<<<(n + 3) / 4, 256, 0, stream>>>(off, csr, deg, x, agg, n);
    k_node<<<512, 1024, 0, stream>>>(agg, h, Az, Ar, Ah, bz, br, bh,
                                     Wlz, Wlr, Wlh, Whead, bhead,
                                     out_head, out_h, n);
}

// Round 3
// 453.371 us; speedup vs baseline: 1.5933x; 1.3123x over previous
//
#include <hip/hip_runtime.h>
#include <hip/hip_fp16.h>
#include <stdint.h>

typedef unsigned long long u64;
typedef _Float16 half8 __attribute__((ext_vector_type(8)));
typedef float f32x4 __attribute__((ext_vector_type(4)));

__device__ __forceinline__ float sigm(float x) { return 1.0f / (1.0f + __expf(-x)); }
__device__ __forceinline__ float tanhfast(float x) { return 1.0f - 2.0f / (__expf(2.0f * x) + 1.0f); }

// Build fragment-packed fp16 weight buffers:
// B1[128][192]: rows 0-63 = [Wcz@Wlz_top | Wcr@Wlr_top | Wch@Wlh_top], rows 64-127 = [Wlz_bot | Wlr_bot | 0]
// B2[64][64]  = Wlh_bot
// bias[192]   = [bcz@Wlz_top+blz | bcr@Wlr_top+blr | bch@Wlh_top+blh]
// Frag packing: element (k, nc) -> buf[((kt*NT + nt)*64 + lane)*8 + j], kt=k>>5, nt=nc>>4,
//   lane = ((k>>3)&3)<<4 | (nc&15), j = k&7   (A/B fragment order for mfma_f32_16x16x32_f16)
__global__ void k_weights(const float* __restrict__ Wcz, const float* __restrict__ bcz,
                          const float* __restrict__ Wcr, const float* __restrict__ bcr,
                          const float* __restrict__ Wch, const float* __restrict__ bch,
                          const float* __restrict__ Wlz, const float* __restrict__ blz,
                          const float* __restrict__ Wlr, const float* __restrict__ blr,
                          const float* __restrict__ Wlh, const float* __restrict__ blh,
                          __half* __restrict__ B1f, __half* __restrict__ B2f,
                          float* __restrict__ bias) {
    int tid = blockIdx.x * 256 + threadIdx.x;
    if (tid < 24576) {
        int k = tid / 192, nc = tid % 192;
        int g = nc >> 6, j = nc & 63;
        const float* Wc = (g == 0) ? Wcz : (g == 1) ? Wcr : Wch;
        const float* Wl = (g == 0) ? Wlz : (g == 1) ? Wlr : Wlh;
        float v;
        if (k < 64) {
            float acc = 0.f;
            for (int m = 0; m < 64; m++) acc += Wc[k * 64 + m] * Wl[m * 64 + j];
            v = acc;
        } else {
            v = (g < 2) ? Wl[k * 64 + j] : 0.f;
        }
        int kt = k >> 5, nt = nc >> 4;
        int lane = (((k >> 3) & 3) << 4) | (nc & 15);
        B1f[(((kt * 12 + nt) * 64 + lane) << 3) + (k & 7)] = (__half)v;
    } else if (tid < 24576 + 4096) {
        int t = tid - 24576;
        int k = t >> 6, nc = t & 63;
        float v = Wlh[(64 + k) * 64 + nc];
        int kt = k >> 5, nt = nc >> 4;
        int lane = (((k >> 3) & 3) << 4) | (nc & 15);
        B2f[(((kt * 4 + nt) * 64 + lane) << 3) + (k & 7)] = (__half)v;
    } else if (tid < 24576 + 4096 + 192) {
        int t = tid - 24576 - 4096;
        int g = t >> 6, j = t & 63;
        const float* bc = (g == 0) ? bcz : (g == 1) ? bcr : bch;
        const float* Wl = (g == 0) ? Wlz : (g == 1) ? Wlr : Wlh;
        const float* bl = (g == 0) ? blz : (g == 1) ? blr : blh;
        float acc = bl[j];
        for (int m = 0; m < 64; m++) acc += bc[m] * Wl[m * 64 + j];
        bias[t] = acc;
    }
}

// init deg/cnt/off AND convert h -> fp16 into aggh[node][64..127]
__global__ void k_init(const float* __restrict__ h, __half* __restrict__ aggh,
                       float* __restrict__ deg, int* __restrict__ cnt, int* __restrict__ off, int n) {
    int i = blockIdx.x * blockDim.x + threadIdx.x;
    if (i < n * 64) aggh[((size_t)(i >> 6) << 7) + 64 + (i & 63)] = (__half)h[i];
    if (i < n) { deg[i] = 1.0f; cnt[i] = 0; }
    if (i == 0) off[0] = 0;
}

__global__ void k_count(const int* __restrict__ dst, const float* __restrict__ ew,
                        float* __restrict__ deg, int* __restrict__ cnt, int E) {
    int e = blockIdx.x * blockDim.x + threadIdx.x;
    if (e < E) {
        int d = dst[e];
        unsafeAtomicAdd(&deg[d], ew[e]);
        atomicAdd(&cnt[d], 1);
    }
}

// per-block inclusive scan of cnt into off[i+1]; also deg -> rsqrt(deg) fused
__global__ void __launch_bounds__(1024) k_scan1(const int* __restrict__ cnt, int* __restrict__ off,
                                                int* __restrict__ bsum, float* __restrict__ deg, int n) {
    __shared__ int sm[1024];
    int t = threadIdx.x;
    int i = blockIdx.x * 1024 + t;
    if (i < n) deg[i] = rsqrtf(deg[i]);
    int v = (i < n) ? cnt[i] : 0;
    sm[t] = v; __syncthreads();
    for (int s = 1; s < 1024; s <<= 1) {
        int u = (t >= s) ? sm[t - s] : 0;
        __syncthreads();
        sm[t] += u;
        __syncthreads();
    }
    if (i < n) off[i + 1] = sm[t];
    if (t == 1023) bsum[blockIdx.x] = sm[1023];
}

__global__ void __launch_bounds__(128) k_scan2(int* __restrict__ bsum, int nb) {
    __shared__ int sm[128];
    int t = threadIdx.x;
    int v = (t < nb) ? bsum[t] : 0;
    sm[t] = v; __syncthreads();
    for (int s = 1; s < 128; s <<= 1) {
        int u = (t >= s) ? sm[t - s] : 0;
        __syncthreads();
        sm[t] += u;
        __syncthreads();
    }
    if (t < nb) bsum[t] = sm[t] - v;
}

__global__ void __launch_bounds__(1024) k_scan3(int* __restrict__ off, const int* __restrict__ bsum,
                                                int* __restrict__ cur, int n) {
    int i = blockIdx.x * 1024 + threadIdx.x;
    if (i < n) {
        int v = off[i + 1] + bsum[blockIdx.x];
        off[i + 1] = v;
        cur[i + 1] = v;
    }
    if (i == 0) cur[0] = 0;
}

__global__ void k_scatter(const int* __restrict__ src, const int* __restrict__ dst,
                          const float* __restrict__ ew, const float* __restrict__ dinv,
                          int* __restrict__ cur, u64* __restrict__ csr, int E) {
    int e = blockIdx.x * blockDim.x + threadIdx.x;
    if (e < E) {
        int s = src[e], d = dst[e];
        float nrm = dinv[s] * ew[e] * dinv[d];
        int p = atomicAdd(&cur[d], 1);
        csr[p] = (u64)(unsigned)s | ((u64)__float_as_uint(nrm) << 32);
    }
}

// one wave per dst node; writes fp16 agg into aggh[node][0..63]
__global__ void __launch_bounds__(256) k_gather(const int* __restrict__ off, const u64* __restrict__ csr,
                                                const float* __restrict__ dinv, const float* __restrict__ x,
                                                __half* __restrict__ aggh, int n) {
    int lane = threadIdx.x & 63;
    int wid = __builtin_amdgcn_readfirstlane(threadIdx.x >> 6);
    int d = blockIdx.x * 4 + wid;
    if (d >= n) return;
    int o0 = off[d], o1 = off[d + 1];
    float di = dinv[d];
    float acc0 = di * di * x[(size_t)d * 64 + lane];
    float acc1 = 0.f, acc2 = 0.f, acc3 = 0.f;
    int e = o0;
    for (; e + 4 <= o1; e += 4) {
        u64 m0 = csr[e + 0], m1 = csr[e + 1], m2 = csr[e + 2], m3 = csr[e + 3];
        float n0 = __uint_as_float((unsigned)(m0 >> 32));
        float n1 = __uint_as_float((unsigned)(m1 >> 32));
        float n2 = __uint_as_float((unsigned)(m2 >> 32));
        float n3 = __uint_as_float((unsigned)(m3 >> 32));
        acc0 += n0 * x[(size_t)(unsigned)m0 * 64 + lane];
        acc1 += n1 * x[(size_t)(unsigned)m1 * 64 + lane];
        acc2 += n2 * x[(size_t)(unsigned)m2 * 64 + lane];
        acc3 += n3 * x[(size_t)(unsigned)m3 * 64 + lane];
    }
    for (; e < o1; e++) {
        u64 m = csr[e];
        acc0 += __uint_as_float((unsigned)(m >> 32)) * x[(size_t)(unsigned)m * 64 + lane];
    }
    aggh[((size_t)d << 7) + lane] = (__half)((acc0 + acc1) + (acc2 + acc3));
}

// MFMA gate kernel: GEMM1 [64nodes x 128] @ B1[128x192] -> z|r|t_a; hr=h*sigm(r);
// GEMM2 hr @ B2[64x64] accumulated into t; epilogue tanh/blend/relu/head.
__global__ void __launch_bounds__(256, 2) k_node(
        const __half* __restrict__ aggh,
        const __half* __restrict__ B1f_g, const __half* __restrict__ B2f_g,
        const float* __restrict__ bias_g, const float* __restrict__ Whead,
        const float* __restrict__ bhead,
        float* __restrict__ out_head, float* __restrict__ out_h, int n) {

    __shared__ __half B1s[24576];          // 48 KB
    __shared__ __half B2s[4096];           // 8 KB
    __shared__ float biasS[192];
    __shared__ float whS[64];
    __shared__ __half hrb[4][16 * 72];     // per-wave C->A relayout buffer (stride 72 kills conflicts)

    int tid = threadIdx.x;
    {
        const uint4* s1 = (const uint4*)B1f_g; uint4* d1 = (uint4*)B1s;
        for (int i = tid; i < 3072; i += 256) d1[i] = s1[i];
        const uint4* s2 = (const uint4*)B2f_g; uint4* d2 = (uint4*)B2s;
        for (int i = tid; i < 512; i += 256) d2[i] = s2[i];
        if (tid < 192) biasS[tid] = bias_g[tid];
        if (tid < 64) whS[tid] = Whead[tid];
    }
    __syncthreads();

    int lane = tid & 63;
    int wave = tid >> 6;
    int quad = lane >> 4;
    int l15 = lane & 15;

    float bz4[4], br4[4], bh4[4], wh4[4];
#pragma unroll
    for (int nt = 0; nt < 4; nt++) {
        bz4[nt] = biasS[nt * 16 + l15];
        br4[nt] = biasS[64 + nt * 16 + l15];
        bh4[nt] = biasS[128 + nt * 16 + l15];
        wh4[nt] = whS[nt * 16 + l15];
    }
    float bhv = bhead[0];
    __half* myhr = &hrb[wave][0];
    const half8* B1v = (const half8*)B1s;
    const half8* B2v = (const half8*)B2s;

    int tiles = (n + 63) >> 6;
    for (int t = blockIdx.x; t < tiles; t += gridDim.x) {
        int mbase = t * 64 + wave * 16;
        if (mbase >= n) continue;   // n % 16 == 0 so m-tiles are all-or-nothing

        // A fragments: lane holds A[m=l15][k=quad*8+j] per 32-wide k-tile
        const half8* arow = (const half8*)(aggh + (((size_t)(mbase + l15)) << 7) + (quad << 3));
        half8 a0 = arow[0], a1 = arow[4], a2 = arow[8], a3 = arow[12];

        f32x4 acc[12];
#pragma unroll
        for (int nt = 0; nt < 12; nt++) acc[nt] = (f32x4){0.f, 0.f, 0.f, 0.f};

#pragma unroll
        for (int nt = 0; nt < 12; nt++) {
            acc[nt] = __builtin_amdgcn_mfma_f32_16x16x32_f16(a0, B1v[(0 * 12 + nt) * 64 + lane], acc[nt], 0, 0, 0);
            acc[nt] = __builtin_amdgcn_mfma_f32_16x16x32_f16(a1, B1v[(1 * 12 + nt) * 64 + lane], acc[nt], 0, 0, 0);
            acc[nt] = __builtin_amdgcn_mfma_f32_16x16x32_f16(a2, B1v[(2 * 12 + nt) * 64 + lane], acc[nt], 0, 0, 0);
            acc[nt] = __builtin_amdgcn_mfma_f32_16x16x32_f16(a3, B1v[(3 * 12 + nt) * 64 + lane], acc[nt], 0, 0, 0);
        }

        // h values at C-layout positions: (m = mbase+quad*4+r, c = nt*16+l15)
        float hv[4][4];
#pragma unroll
        for (int nt = 0; nt < 4; nt++)
#pragma unroll
            for (int r = 0; r < 4; r++)
                hv[nt][r] = (float)aggh[(((size_t)(mbase + quad * 4 + r)) << 7) + 64 + nt * 16 + l15];

        // Z, R; hr -> LDS (C-layout positions -> [m_local][c] fp16)
        float Z[4][4];
#pragma unroll
        for (int nt = 0; nt < 4; nt++)
#pragma unroll
            for (int r = 0; r < 4; r++) {
                Z[nt][r] = sigm(acc[nt][r] + bz4[nt]);
                float R = sigm(acc[4 + nt][r] + br4[nt]);
                myhr[(quad * 4 + r) * 72 + nt * 16 + l15] = (__half)(hv[nt][r] * R);
            }
        __builtin_amdgcn_s_waitcnt(0);   // drain lgkm before cross-lane LDS read (same wave)

        // hr A-fragments
        half8 a2f0 = *(const half8*)(myhr + l15 * 72 + quad * 8);
        half8 a2f1 = *(const half8*)(myhr + l15 * 72 + 32 + quad * 8);

#pragma unroll
        for (int nt = 0; nt < 4; nt++) {
            acc[8 + nt] = __builtin_amdgcn_mfma_f32_16x16x32_f16(a2f0, B2v[(0 * 4 + nt) * 64 + lane], acc[8 + nt], 0, 0, 0);
            acc[8 + nt] = __builtin_amdgcn_mfma_f32_16x16x32_f16(a2f1, B2v[(1 * 4 + nt) * 64 + lane], acc[8 + nt], 0, 0, 0);
        }

        // epilogue: h_new = Z*h + (1-Z)*tanh(t+bh); head = relu(h_new) . Whead + bhead
        float pr0 = 0.f, pr1 = 0.f, pr2 = 0.f, pr3 = 0.f;
#pragma unroll
        for (int nt = 0; nt < 4; nt++) {
#pragma unroll
            for (int r = 0; r < 4; r++) {
                float Ht = tanhfast(acc[8 + nt][r] + bh4[nt]);
                float z = Z[nt][r];
                float hn = z * hv[nt][r] + (1.f - z) * Ht;
                out_h[((size_t)(mbase + quad * 4 + r)) * 64 + nt * 16 + l15] = hn;
                float rv = fmaxf(hn, 0.f) * wh4[nt];
                if (r == 0) pr0 += rv; else if (r == 1) pr1 += rv; else if (r == 2) pr2 += rv; else pr3 += rv;
            }
        }
#pragma unroll
        for (int o = 1; o < 16; o <<= 1) {
            pr0 += __shfl_xor(pr0, o);
            pr1 += __shfl_xor(pr1, o);
            pr2 += __shfl_xor(pr2, o);
            pr3 += __shfl_xor(pr3, o);
        }
        if (l15 == 0) {
            out_head[mbase + quad * 4 + 0] = pr0 + bhv;
            out_head[mbase + quad * 4 + 1] = pr1 + bhv;
            out_head[mbase + quad * 4 + 2] = pr2 + bhv;
            out_head[mbase + quad * 4 + 3] = pr3 + bhv;
        }
    }
}

extern "C" void kernel_launch(void* const* d_in, const int* in_sizes, int n_in,
                              void* d_out, int out_size, void* d_ws, size_t ws_size,
                              hipStream_t stream) {
    const float* x     = (const float*)d_in[0];
    const int*   src   = (const int*)d_in[1];
    const int*   dst   = (const int*)d_in[2];
    const float* ew    = (const float*)d_in[3];
    const float* h     = (const float*)d_in[4];
    const float* Wcz   = (const float*)d_in[5];
    const float* bcz   = (const float*)d_in[6];
    const float* Wcr   = (const float*)d_in[7];
    const float* bcr   = (const float*)d_in[8];
    const float* Wch   = (const float*)d_in[9];
    const float* bch   = (const float*)d_in[10];
    const float* Wlz   = (const float*)d_in[11];
    const float* blz   = (const float*)d_in[12];
    const float* Wlr   = (const float*)d_in[13];
    const float* blr   = (const float*)d_in[14];
    const float* Wlh   = (const float*)d_in[15];
    const float* blh   = (const float*)d_in[16];
    const float* Whead = (const float*)d_in[17];
    const float* bhead = (const float*)d_in[18];

    int E = in_sizes[1];
    int n = in_sizes[4] / 64;                 // 100000 nodes

    // workspace layout
    __half* aggh = (__half*)d_ws;             // n*128 fp16: [agg | h] interleaved per node
    float* deg = (float*)(aggh + (size_t)n * 128);
    int*   cnt = (int*)(deg + n);
    int*   off = cnt + n;
    int*   cur = off + n + 1;
    int*   bsum = cur + n + 1;
    u64*   csr = (u64*)(((uintptr_t)(bsum + 128) + 15) & ~(uintptr_t)15);  // E u64
    __half* B1f = (__half*)(csr + E);         // 24576 fp16
    __half* B2f = B1f + 24576;                // 4096 fp16
    float* bias = (float*)(B2f + 4096);       // 192 f32

    float* out_head = (float*)d_out;          // [n]
    float* out_h    = out_head + n;           // [n*64]

    int nb = (n + 1023) / 1024;

    k_weights<<<113, 256, 0, stream>>>(Wcz, bcz, Wcr, bcr, Wch, bch,
                                       Wlz, blz, Wlr, blr, Wlh, blh, B1f, B2f, bias);
    k_init<<<(n * 64 + 255) / 256, 256, 0, stream>>>(h, aggh, deg, cnt, off, n);
    k_count<<<(E + 255) / 256, 256, 0, stream>>>(dst, ew, deg, cnt, E);
    k_scan1<<<nb, 1024, 0, stream>>>(cnt, off, bsum, deg, n);
    k_scan2<<<1, 128, 0, stream>>>(bsum, nb);
    k_scan3<<<nb, 1024, 0, stream>>>(off, bsum, cur, n);
    k_scatter<<<(E + 255) / 256, 256, 0, stream>>>(src, dst, ew, deg, cur, csr, E);
    k_gather<<<(n + 3) / 4, 256, 0, stream>>>(off, csr, deg, x, aggh, n);
    k_node<<<512, 256, 0, stream>>>(aggh, B1f, B2f, bias, Whead, bhead,
                                    out_head, out_h, n);
}

// Round 4
// 353.535 us; speedup vs baseline: 2.0432x; 1.2824x over previous
//
#include <hip/hip_runtime.h>
#include <hip/hip_fp16.h>
#include <stdint.h>

typedef unsigned long long u64;
typedef _Float16 half8 __attribute__((ext_vector_type(8)));
typedef float f32x4 __attribute__((ext_vector_type(4)));

__device__ __forceinline__ float sigm(float x) { return 1.0f / (1.0f + __expf(-x)); }
__device__ __forceinline__ float tanhfast(float x) { return 1.0f - 2.0f / (__expf(2.0f * x) + 1.0f); }
__device__ __forceinline__ int rli(int v, int k) { return __builtin_amdgcn_readlane(v, k); }
__device__ __forceinline__ float rlf(float v, int k) {
    return __int_as_float(__builtin_amdgcn_readlane(__float_as_int(v), k));
}

// Build fragment-packed fp16 weight buffers (see round-2 comment for layout).
__global__ void k_weights(const float* __restrict__ Wcz, const float* __restrict__ bcz,
                          const float* __restrict__ Wcr, const float* __restrict__ bcr,
                          const float* __restrict__ Wch, const float* __restrict__ bch,
                          const float* __restrict__ Wlz, const float* __restrict__ blz,
                          const float* __restrict__ Wlr, const float* __restrict__ blr,
                          const float* __restrict__ Wlh, const float* __restrict__ blh,
                          __half* __restrict__ B1f, __half* __restrict__ B2f,
                          float* __restrict__ bias) {
    int tid = blockIdx.x * 256 + threadIdx.x;
    if (tid < 24576) {
        int k = tid / 192, nc = tid % 192;
        int g = nc >> 6, j = nc & 63;
        const float* Wc = (g == 0) ? Wcz : (g == 1) ? Wcr : Wch;
        const float* Wl = (g == 0) ? Wlz : (g == 1) ? Wlr : Wlh;
        float v;
        if (k < 64) {
            float acc = 0.f;
            for (int m = 0; m < 64; m++) acc += Wc[k * 64 + m] * Wl[m * 64 + j];
            v = acc;
        } else {
            v = (g < 2) ? Wl[k * 64 + j] : 0.f;
        }
        int kt = k >> 5, nt = nc >> 4;
        int lane = (((k >> 3) & 3) << 4) | (nc & 15);
        B1f[(((kt * 12 + nt) * 64 + lane) << 3) + (k & 7)] = (__half)v;
    } else if (tid < 24576 + 4096) {
        int t = tid - 24576;
        int k = t >> 6, nc = t & 63;
        float v = Wlh[(64 + k) * 64 + nc];
        int kt = k >> 5, nt = nc >> 4;
        int lane = (((k >> 3) & 3) << 4) | (nc & 15);
        B2f[(((kt * 4 + nt) * 64 + lane) << 3) + (k & 7)] = (__half)v;
    } else if (tid < 24576 + 4096 + 192) {
        int t = tid - 24576 - 4096;
        int g = t >> 6, j = t & 63;
        const float* bc = (g == 0) ? bcz : (g == 1) ? bcr : bch;
        const float* Wl = (g == 0) ? Wlz : (g == 1) ? Wlr : Wlh;
        const float* bl = (g == 0) ? blz : (g == 1) ? blr : blh;
        float acc = bl[j];
        for (int m = 0; m < 64; m++) acc += bc[m] * Wl[m * 64 + j];
        bias[t] = acc;
    }
}

// zero cnt, h -> fp16 aggh[node][64..127], x -> fp16 xh
__global__ void k_init(const float* __restrict__ x, const float* __restrict__ h,
                       __half* __restrict__ xh, __half* __restrict__ aggh,
                       int* __restrict__ cnt, int n) {
    int i = blockIdx.x * blockDim.x + threadIdx.x;
    if (i < n * 64) {
        aggh[((size_t)(i >> 6) << 7) + 64 + (i & 63)] = (__half)h[i];
        xh[i] = (__half)x[i];
    }
    if (i < n) cnt[i] = 0;
}

// single ticketed pass: slots[d*64 + p] = (src, ew)
__global__ void k_fill(const int* __restrict__ src, const int* __restrict__ dst,
                       const float* __restrict__ ew,
                       int* __restrict__ cnt, u64* __restrict__ slots, int E) {
    int e = blockIdx.x * blockDim.x + threadIdx.x;
    if (e < E) {
        int d = dst[e];
        int p = atomicAdd(&cnt[d], 1);
        if (p < 64)
            slots[((size_t)d << 6) + p] = (u64)(unsigned)src[e] | ((u64)__float_as_uint(ew[e]) << 32);
    }
}

// wave per node: dinv[d] = rsqrt(1 + sum ew) via coalesced slot read + shuffle reduce
__global__ void __launch_bounds__(256) k_deg(const int* __restrict__ cnt, const u64* __restrict__ slots,
                                             float* __restrict__ dinv, int n) {
    int lane = threadIdx.x & 63;
    int d = blockIdx.x * 4 + (threadIdx.x >> 6);
    if (d >= n) return;
    int c = min(cnt[d], 64);
    u64 m = slots[((size_t)d << 6) + lane];
    float w = (lane < c) ? __uint_as_float((unsigned)(m >> 32)) : 0.f;
#pragma unroll
    for (int o = 32; o; o >>= 1) w += __shfl_xor(w, o);
    if (lane == 0) dinv[d] = rsqrtf(1.0f + w);
}

// wave per node: agg = dinv^2*x[d] + sum nrm*x[src]; metadata via 1 coalesced load + readlane
__global__ void __launch_bounds__(256) k_gather(const int* __restrict__ cnt, const u64* __restrict__ slots,
                                                const float* __restrict__ dinv, const __half* __restrict__ xh,
                                                __half* __restrict__ aggh, int n) {
    int lane = threadIdx.x & 63;
    int d = blockIdx.x * 4 + (threadIdx.x >> 6);
    if (d >= n) return;
    int c = min(cnt[d], 64);
    u64 m = slots[((size_t)d << 6) + lane];
    int s_l = (lane < c) ? (int)(unsigned)m : 0;
    float ew_l = (lane < c) ? __uint_as_float((unsigned)(m >> 32)) : 0.f;
    float dd = dinv[d];
    float nrm_l = ew_l * dinv[s_l] * dd;

    float acc0 = dd * dd * (float)xh[((size_t)d << 6) + lane];
    float acc1 = 0.f, acc2 = 0.f, acc3 = 0.f;
    int k = 0;
    for (; k + 4 <= c; k += 4) {
        int s0 = rli(s_l, k), s1 = rli(s_l, k + 1), s2 = rli(s_l, k + 2), s3 = rli(s_l, k + 3);
        float n0 = rlf(nrm_l, k), n1 = rlf(nrm_l, k + 1), n2 = rlf(nrm_l, k + 2), n3 = rlf(nrm_l, k + 3);
        acc0 += n0 * (float)xh[((size_t)s0 << 6) + lane];
        acc1 += n1 * (float)xh[((size_t)s1 << 6) + lane];
        acc2 += n2 * (float)xh[((size_t)s2 << 6) + lane];
        acc3 += n3 * (float)xh[((size_t)s3 << 6) + lane];
    }
    for (; k < c; k++) {
        int s0 = rli(s_l, k);
        float n0 = rlf(nrm_l, k);
        acc0 += n0 * (float)xh[((size_t)s0 << 6) + lane];
    }
    aggh[((size_t)d << 7) + lane] = (__half)((acc0 + acc1) + (acc2 + acc3));
}

// MFMA gate kernel (unchanged from round 3)
__global__ void __launch_bounds__(256, 2) k_node(
        const __half* __restrict__ aggh,
        const __half* __restrict__ B1f_g, const __half* __restrict__ B2f_g,
        const float* __restrict__ bias_g, const float* __restrict__ Whead,
        const float* __restrict__ bhead,
        float* __restrict__ out_head, float* __restrict__ out_h, int n) {

    __shared__ __half B1s[24576];
    __shared__ __half B2s[4096];
    __shared__ float biasS[192];
    __shared__ float whS[64];
    __shared__ __half hrb[4][16 * 72];

    int tid = threadIdx.x;
    {
        const uint4* s1 = (const uint4*)B1f_g; uint4* d1 = (uint4*)B1s;
        for (int i = tid; i < 3072; i += 256) d1[i] = s1[i];
        const uint4* s2 = (const uint4*)B2f_g; uint4* d2 = (uint4*)B2s;
        for (int i = tid; i < 512; i += 256) d2[i] = s2[i];
        if (tid < 192) biasS[tid] = bias_g[tid];
        if (tid < 64) whS[tid] = Whead[tid];
    }
    __syncthreads();

    int lane = tid & 63;
    int wave = tid >> 6;
    int quad = lane >> 4;
    int l15 = lane & 15;

    float bz4[4], br4[4], bh4[4], wh4[4];
#pragma unroll
    for (int nt = 0; nt < 4; nt++) {
        bz4[nt] = biasS[nt * 16 + l15];
        br4[nt] = biasS[64 + nt * 16 + l15];
        bh4[nt] = biasS[128 + nt * 16 + l15];
        wh4[nt] = whS[nt * 16 + l15];
    }
    float bhv = bhead[0];
    __half* myhr = &hrb[wave][0];
    const half8* B1v = (const half8*)B1s;
    const half8* B2v = (const half8*)B2s;

    int tiles = (n + 63) >> 6;
    for (int t = blockIdx.x; t < tiles; t += gridDim.x) {
        int mbase = t * 64 + wave * 16;
        if (mbase >= n) continue;

        const half8* arow = (const half8*)(aggh + (((size_t)(mbase + l15)) << 7) + (quad << 3));
        half8 a0 = arow[0], a1 = arow[4], a2 = arow[8], a3 = arow[12];

        f32x4 acc[12];
#pragma unroll
        for (int nt = 0; nt < 12; nt++) acc[nt] = (f32x4){0.f, 0.f, 0.f, 0.f};

#pragma unroll
        for (int nt = 0; nt < 12; nt++) {
            acc[nt] = __builtin_amdgcn_mfma_f32_16x16x32_f16(a0, B1v[(0 * 12 + nt) * 64 + lane], acc[nt], 0, 0, 0);
            acc[nt] = __builtin_amdgcn_mfma_f32_16x16x32_f16(a1, B1v[(1 * 12 + nt) * 64 + lane], acc[nt], 0, 0, 0);
            acc[nt] = __builtin_amdgcn_mfma_f32_16x16x32_f16(a2, B1v[(2 * 12 + nt) * 64 + lane], acc[nt], 0, 0, 0);
            acc[nt] = __builtin_amdgcn_mfma_f32_16x16x32_f16(a3, B1v[(3 * 12 + nt) * 64 + lane], acc[nt], 0, 0, 0);
        }

        float hv[4][4];
#pragma unroll
        for (int nt = 0; nt < 4; nt++)
#pragma unroll
            for (int r = 0; r < 4; r++)
                hv[nt][r] = (float)aggh[(((size_t)(mbase + quad * 4 + r)) << 7) + 64 + nt * 16 + l15];

        float Z[4][4];
#pragma unroll
        for (int nt = 0; nt < 4; nt++)
#pragma unroll
            for (int r = 0; r < 4; r++) {
                Z[nt][r] = sigm(acc[nt][r] + bz4[nt]);
                float R = sigm(acc[4 + nt][r] + br4[nt]);
                myhr[(quad * 4 + r) * 72 + nt * 16 + l15] = (__half)(hv[nt][r] * R);
            }
        __builtin_amdgcn_s_waitcnt(0);

        half8 a2f0 = *(const half8*)(myhr + l15 * 72 + quad * 8);
        half8 a2f1 = *(const half8*)(myhr + l15 * 72 + 32 + quad * 8);

#pragma unroll
        for (int nt = 0; nt < 4; nt++) {
            acc[8 + nt] = __builtin_amdgcn_mfma_f32_16x16x32_f16(a2f0, B2v[(0 * 4 + nt) * 64 + lane], acc[8 + nt], 0, 0, 0);
            acc[8 + nt] = __builtin_amdgcn_mfma_f32_16x16x32_f16(a2f1, B2v[(1 * 4 + nt) * 64 + lane], acc[8 + nt], 0, 0, 0);
        }

        float pr0 = 0.f, pr1 = 0.f, pr2 = 0.f, pr3 = 0.f;
#pragma unroll
        for (int nt = 0; nt < 4; nt++) {
#pragma unroll
            for (int r = 0; r < 4; r++) {
                float Ht = tanhfast(acc[8 + nt][r] + bh4[nt]);
                float z = Z[nt][r];
                float hn = z * hv[nt][r] + (1.f - z) * Ht;
                out_h[((size_t)(mbase + quad * 4 + r)) * 64 + nt * 16 + l15] = hn;
                float rv = fmaxf(hn, 0.f) * wh4[nt];
                if (r == 0) pr0 += rv; else if (r == 1) pr1 += rv; else if (r == 2) pr2 += rv; else pr3 += rv;
            }
        }
#pragma unroll
        for (int o = 1; o < 16; o <<= 1) {
            pr0 += __shfl_xor(pr0, o);
            pr1 += __shfl_xor(pr1, o);
            pr2 += __shfl_xor(pr2, o);
            pr3 += __shfl_xor(pr3, o);
        }
        if (l15 == 0) {
            out_head[mbase + quad * 4 + 0] = pr0 + bhv;
            out_head[mbase + quad * 4 + 1] = pr1 + bhv;
            out_head[mbase + quad * 4 + 2] = pr2 + bhv;
            out_head[mbase + quad * 4 + 3] = pr3 + bhv;
        }
    }
}

extern "C" void kernel_launch(void* const* d_in, const int* in_sizes, int n_in,
                              void* d_out, int out_size, void* d_ws, size_t ws_size,
                              hipStream_t stream) {
    const float* x     = (const float*)d_in[0];
    const int*   src   = (const int*)d_in[1];
    const int*   dst   = (const int*)d_in[2];
    const float* ew    = (const float*)d_in[3];
    const float* h     = (const float*)d_in[4];
    const float* Wcz   = (const float*)d_in[5];
    const float* bcz   = (const float*)d_in[6];
    const float* Wcr   = (const float*)d_in[7];
    const float* bcr   = (const float*)d_in[8];
    const float* Wch   = (const float*)d_in[9];
    const float* bch   = (const float*)d_in[10];
    const float* Wlz   = (const float*)d_in[11];
    const float* blz   = (const float*)d_in[12];
    const float* Wlr   = (const float*)d_in[13];
    const float* blr   = (const float*)d_in[14];
    const float* Wlh   = (const float*)d_in[15];
    const float* blh   = (const float*)d_in[16];
    const float* Whead = (const float*)d_in[17];
    const float* bhead = (const float*)d_in[18];

    int E = in_sizes[1];
    int n = in_sizes[4] / 64;                 // 100000 nodes

    // workspace layout
    __half* aggh = (__half*)d_ws;             // n*128 fp16: [agg | h]
    __half* xh   = aggh + (size_t)n * 128;    // n*64 fp16
    u64*   slots = (u64*)(xh + (size_t)n * 64);   // n*64 u64 (8B-aligned: offset = n*192*2 bytes)
    float* dinv  = (float*)(slots + (size_t)n * 64);
    int*   cnt   = (int*)(dinv + n);
    __half* B1f  = (__half*)(cnt + n);        // 24576 fp16
    __half* B2f  = B1f + 24576;               // 4096 fp16
    float* bias  = (float*)(B2f + 4096);      // 192 f32

    float* out_head = (float*)d_out;          // [n]
    float* out_h    = out_head + n;           // [n*64]

    k_weights<<<113, 256, 0, stream>>>(Wcz, bcz, Wcr, bcr, Wch, bch,
                                       Wlz, blz, Wlr, blr, Wlh, blh, B1f, B2f, bias);
    k_init<<<(n * 64 + 255) / 256, 256, 0, stream>>>(x, h, xh, aggh, cnt, n);
    k_fill<<<(E + 255) / 256, 256, 0, stream>>>(src, dst, ew, cnt, slots, E);
    k_deg<<<(n + 3) / 4, 256, 0, stream>>>(cnt, slots, dinv, n);
    k_gather<<<(n + 3) / 4, 256, 0, stream>>>(cnt, slots, dinv, xh, aggh, n);
    k_node<<<512, 256, 0, stream>>>(aggh, B1f, B2f, bias, Whead, bhead,
                                    out_head, out_h, n);
}